// Round 4
// baseline (94.204 us; speedup 1.0000x reference)
//
#include <hip/hip_runtime.h>
#include <hip/hip_bf16.h>
#include <math.h>

// Problem constants (fixed by setup_inputs)
constexpr int N  = 64;
constexpr int V  = 25;
constexpr int K  = 3;
constexpr int CT = 32768;            // C*T
constexpr int VK = 12;               // int(0.5 * 25)
constexpr int SPLIT = 32;            // score-pass split along ct per sample
constexpr int ROWS  = 256;           // rows per LDS tile (64 rows per wave)
constexpr int NBLK_G = N * (CT / ROWS);   // 8192 gather blocks

// ---------------- ws layout (bytes) ----------------
// partial_t : N*V*SPLIT floats = 51200 floats @ 0   (204800 B)  layout [n][v][s]
// p2partial : SPLIT floats @ 204800                 (128 B)

__device__ __forceinline__ void gload_lds16(const float* g, float* l) {
    // async global->LDS DMA: 16B per lane; LDS dest = wave-uniform base + lane*16
    __builtin_amdgcn_global_load_lds(
        (const __attribute__((address_space(1))) void*)g,
        (__attribute__((address_space(3))) void*)l, 16, 0, 0);
}

// Wave w stages its own 64 rows (1600 floats = 400 float4s): 6 full issues + 16-lane tail.
// Region is wave-exclusive -> no cross-wave sync needed, ever.
__device__ __forceinline__ void stage_wave(const float* __restrict__ gsrc, float* lds,
                                           int wave, int lane) {
    const float* gw = gsrc + (size_t)wave * 1600;
    float* lw = lds + wave * 1600;
    #pragma unroll
    for (int i = 0; i < 6; ++i)
        gload_lds16(gw + (size_t)(i * 64 + lane) * 4, lw + i * 256);
    if (lane < 16)
        gload_lds16(gw + (size_t)(384 + lane) * 4, lw + 384 * 4);
}

// Kernel 1: partial raw dots. partial_t[n][v][s] = sum over ct-slice of x[n,ct,v]*p[ct].
// n==0 blocks also write p2partial[s]. Barrier-free tile loop (per-wave LDS regions).
__global__ __launch_bounds__(256) void k_scores(const float* __restrict__ x,
                                                const float* __restrict__ p,
                                                float* __restrict__ partial_t,
                                                float* __restrict__ p2partial) {
    const int n = blockIdx.x / SPLIT;
    const int s = blockIdx.x % SPLIT;
    constexpr int CHUNK = CT / SPLIT;     // 1024
    constexpr int TILES = CHUNK / ROWS;   // 4
    const int ct0 = s * CHUNK;
    const float* xn = x + (size_t)n * CT * V;
    const int tid = threadIdx.x, wave = tid >> 6, lane = tid & 63;

    __shared__ float lds[ROWS * V];       // 25600 B

    float acc[V];
    #pragma unroll
    for (int v = 0; v < V; ++v) acc[v] = 0.f;
    float psq = 0.f;

    for (int tile = 0; tile < TILES; ++tile) {
        const int base_ct = ct0 + tile * ROWS;
        // WAR guard: prior ds_reads must retire before DMA overwrites our region
        asm volatile("s_waitcnt lgkmcnt(0)" ::: "memory");
        stage_wave(xn + (size_t)base_ct * V, lds, wave, lane);
        asm volatile("s_waitcnt vmcnt(0)" ::: "memory");

        const float pv = p[base_ct + tid];
        psq += pv * pv;
        const float* row = lds + tid * V;   // stride 25: bank-conflict-free
        #pragma unroll
        for (int v = 0; v < V; ++v) acc[v] += row[v] * pv;
    }

    #pragma unroll
    for (int v = 0; v < V; ++v) {
        float a = acc[v];
        #pragma unroll
        for (int off = 32; off > 0; off >>= 1) a += __shfl_down(a, off);
        acc[v] = a;
    }
    #pragma unroll
    for (int off = 32; off > 0; off >>= 1) psq += __shfl_down(psq, off);

    __shared__ float red[4][V];
    __shared__ float redp[4];
    if (lane == 0) {
        #pragma unroll
        for (int v = 0; v < V; ++v) red[wave][v] = acc[v];
        redp[wave] = psq;
    }
    __syncthreads();
    if (tid < V) {
        partial_t[((size_t)n * V + tid) * SPLIT + s] =
            red[0][tid] + red[1][tid] + red[2][tid] + red[3][tid];
    }
    if (tid == V && n == 0) {
        p2partial[s] = redp[0] + redp[1] + redp[2] + redp[3];
    }
}

// Per-wave top-12 from transposed partials. Lanes 0..24 hold column sums; returns via
// wave-local LDS scratch (swidx/swyh). Stable descending (ties -> lower index first).
__device__ __forceinline__ void wave_topk(const float* __restrict__ partial_t,
                                          const float* __restrict__ p2partial,
                                          int n, int lane, int* swidx, float* swyh) {
    float s2 = 0.f;
    #pragma unroll
    for (int i = 0; i < SPLIT; ++i) s2 += p2partial[i];

    float my = 0.f;
    if (lane < V) {
        const float4* pb = (const float4*)(partial_t + ((size_t)n * V + lane) * SPLIT);
        #pragma unroll
        for (int i = 0; i < SPLIT / 4; ++i) {
            float4 q = pb[i];
            my += q.x + q.y + q.z + q.w;
        }
    }
    int rank = 0;
    #pragma unroll
    for (int u = 0; u < V; ++u) {
        const float yu = __shfl(my, u);
        if (yu > my || (yu == my && u < lane)) ++rank;
    }
    if (lane < V && rank < VK) {
        swidx[rank] = lane;
        swyh[rank]  = 1.0f / (1.0f + expf(-my * rsqrtf(s2)));
    }
}

// Kernel 2: blocks [0,8192): gather+scale (barrier-free, per-wave regions, topk inline,
//           topk overlapped with the stage DMA). blocks [8192,8384): A_out via wave 0.
__global__ __launch_bounds__(256) void k_gather_aout(const float* __restrict__ x,
                                                     const float* __restrict__ A,
                                                     const float* __restrict__ partial_t,
                                                     const float* __restrict__ p2partial,
                                                     float* __restrict__ xout,
                                                     float* __restrict__ aout) {
    __shared__ float lds[ROWS * V];          // 25600 B (aout path uses first 625 floats)
    __shared__ int   swidx[4][VK];
    __shared__ float swyh[4][VK];
    const int tid = threadIdx.x, wave = tid >> 6, lane = tid & 63;

    if (blockIdx.x < (unsigned)NBLK_G) {
        const int n  = blockIdx.x >> 7;          // 128 tiles per sample
        const int r0 = (blockIdx.x & 127) << 8;  // row base within sample

        // 1) issue stage DMA for this wave's 64 rows
        stage_wave(x + ((size_t)n * CT + r0) * V, lds, wave, lane);
        // 2) topk overlapped with DMA flight time
        wave_topk(partial_t, p2partial, n, lane, swidx[wave], swyh[wave]);
        // 3) wait for DMA + scratch writes (same wave -> no barrier)
        asm volatile("s_waitcnt vmcnt(0) lgkmcnt(0)" ::: "memory");

        // 4) gather: wave w writes output f4s [192w, 192w+192) covering its own rows
        float4* dst = (float4*)(xout + ((size_t)n * CT + r0) * VK);
        #pragma unroll
        for (int j = 0; j < 3; ++j) {
            const int f   = 192 * wave + 64 * j + lane;
            const int row = f / 3;
            const int c0  = (f % 3) * 4;
            float4 o;
            o.x = lds[row * V + swidx[wave][c0 + 0]] * swyh[wave][c0 + 0];
            o.y = lds[row * V + swidx[wave][c0 + 1]] * swyh[wave][c0 + 1];
            o.z = lds[row * V + swidx[wave][c0 + 2]] * swyh[wave][c0 + 2];
            o.w = lds[row * V + swidx[wave][c0 + 3]] * swyh[wave][c0 + 3];
            dst[f] = o;                          // contiguous across lanes: coalesced
        }
    } else {
        if (wave != 0) return;                   // tiny blocks: single wave
        const int b2 = blockIdx.x - NBLK_G;      // [0, 192)
        const int n  = b2 / K;
        const int k  = b2 % K;
        wave_topk(partial_t, p2partial, n, lane, swidx[0], swyh[0]);
        const float* Ak = A + ((size_t)n * K + k) * V * V;
        for (int i = lane; i < V * V; i += 64) lds[i] = Ak[i];
        asm volatile("s_waitcnt vmcnt(0) lgkmcnt(0)" ::: "memory");
        for (int o = lane; o < VK * VK; o += 64) {
            const int a  = o / VK, bc = o % VK;
            const int ia = swidx[0][a], ib = swidx[0][bc];
            float ssum = 0.f;
            #pragma unroll
            for (int m = 0; m < V; ++m) ssum += lds[ia * V + m] * lds[m * V + ib];
            aout[((size_t)n * K + k) * VK * VK + o] = ssum;
        }
    }
}

extern "C" void kernel_launch(void* const* d_in, const int* in_sizes, int n_in,
                              void* d_out, int out_size, void* d_ws, size_t ws_size,
                              hipStream_t stream) {
    const float* x = (const float*)d_in[0];
    const float* A = (const float*)d_in[1];
    const float* p = (const float*)d_in[2];

    float* xout = (float*)d_out;                       // N*CT*VK floats
    float* aout = xout + (size_t)N * CT * VK;          // N*K*VK*VK floats

    char* ws = (char*)d_ws;
    float* partial_t = (float*)(ws);                   // 51200 floats [n][v][s]
    float* p2partial = (float*)(ws + 204800);          // 32 floats

    k_scores<<<N * SPLIT, 256, 0, stream>>>(x, p, partial_t, p2partial);
    k_gather_aout<<<NBLK_G + N * K, 256, 0, stream>>>(x, A, partial_t, p2partial, xout, aout);
}

// Round 6
// 89.126 us; speedup vs baseline: 1.0570x; 1.0570x over previous
//
#include <hip/hip_runtime.h>
#include <hip/hip_bf16.h>
#include <math.h>

// Problem constants (fixed by setup_inputs)
constexpr int N  = 64;
constexpr int V  = 25;
constexpr int K  = 3;
constexpr int CT = 32768;            // C*T
constexpr int VK = 12;               // int(0.5 * 25)
constexpr int SPLIT = 32;            // score-pass split along ct per sample
constexpr int ROWS  = 256;           // rows per LDS tile (64 rows per wave)
constexpr int CHUNK = CT / SPLIT;    // 1024
constexpr int TILES = CHUNK / ROWS;  // 4
constexpr int NBLK_G = N * (CT / ROWS);   // 8192 gather blocks

typedef float f32x4 __attribute__((ext_vector_type(4)));   // NT-store-legal float4

// ---------------- ws layout (bytes) ----------------
// partial_t : N*V*SPLIT floats = 51200 @ 0       (204800 B)  layout [n][v][s]
// p2partial : SPLIT floats @ 204800               (128 B)
// y_hat     : N*VK floats @ 204928                (3072 B)
// idx       : N*VK ints  @ 208000                 (3072 B)

__device__ __forceinline__ void gload_lds16(const float* g, float* l) {
    // async global->LDS DMA: 16B per lane; LDS dest = wave-uniform base + lane*16
    __builtin_amdgcn_global_load_lds(
        (const __attribute__((address_space(1))) void*)g,
        (__attribute__((address_space(3))) void*)l, 16, 0, 0);
}

// Wave stages its own 64 rows (1600 floats = 400 float4s): 6 full issues + 16-lane
// tail = exactly 7 vmcnt increments per call. Region is wave-exclusive.
__device__ __forceinline__ void stage_wave(const float* __restrict__ gsrc, float* ldsbuf,
                                           int wave, int lane) {
    const float* gw = gsrc + (size_t)wave * 1600;
    float* lw = ldsbuf + wave * 1600;
    #pragma unroll
    for (int i = 0; i < 6; ++i)
        gload_lds16(gw + (size_t)(i * 64 + lane) * 4, lw + i * 256);
    if (lane < 16)
        gload_lds16(gw + (size_t)(384 + lane) * 4, lw + 384 * 4);
}

// Kernel 1: partial raw dots, per-wave double-buffered with counted vmcnt (never
// drains mid-loop). partial_t[n][v][s] = sum over ct-slice of x[n,ct,v]*p[ct].
__global__ __launch_bounds__(256) void k_scores(const float* __restrict__ x,
                                                const float* __restrict__ p,
                                                float* __restrict__ partial_t,
                                                float* __restrict__ p2partial) {
    const int n = blockIdx.x / SPLIT;
    const int s = blockIdx.x % SPLIT;
    const int ct0 = s * CHUNK;
    const float* xn = x + (size_t)n * CT * V;
    const int tid = threadIdx.x, wave = tid >> 6, lane = tid & 63;

    __shared__ float lds[2][ROWS * V];       // 2 x 25600 B

    // preload all p values BEFORE the DMA chain so vmcnt counting stays exact
    float pv[TILES];
    #pragma unroll
    for (int t = 0; t < TILES; ++t) pv[t] = p[ct0 + t * ROWS + tid];

    stage_wave(xn + (size_t)(ct0 + 0 * ROWS) * V, lds[0], wave, lane);
    stage_wave(xn + (size_t)(ct0 + 1 * ROWS) * V, lds[1], wave, lane);

    float acc[V];
    #pragma unroll
    for (int v = 0; v < V; ++v) acc[v] = 0.f;
    float psq = 0.f;

    #pragma unroll
    for (int t = 0; t < TILES; ++t) {
        // oldest 7 loads (tile t) complete; up to 7 (tile t+1) stay in flight
        if (t < TILES - 1) asm volatile("s_waitcnt vmcnt(7)" ::: "memory");
        else               asm volatile("s_waitcnt vmcnt(0)" ::: "memory");

        const float pvt = pv[t];
        psq += pvt * pvt;
        const float* row = lds[t & 1] + tid * V;   // stride 25: bank-conflict-free
        #pragma unroll
        for (int v = 0; v < V; ++v) acc[v] += row[v] * pvt;

        if (t + 2 < TILES) {
            // WAR: our ds_reads of this buffer must retire before DMA overwrites it
            asm volatile("s_waitcnt lgkmcnt(0)" ::: "memory");
            stage_wave(xn + (size_t)(ct0 + (t + 2) * ROWS) * V, lds[t & 1], wave, lane);
        }
    }

    #pragma unroll
    for (int v = 0; v < V; ++v) {
        float a = acc[v];
        #pragma unroll
        for (int off = 32; off > 0; off >>= 1) a += __shfl_down(a, off);
        acc[v] = a;
    }
    #pragma unroll
    for (int off = 32; off > 0; off >>= 1) psq += __shfl_down(psq, off);

    __shared__ float red[4][V];
    __shared__ float redp[4];
    if (lane == 0) {
        #pragma unroll
        for (int v = 0; v < V; ++v) red[wave][v] = acc[v];
        redp[wave] = psq;
    }
    __syncthreads();
    if (tid < V) {
        partial_t[((size_t)n * V + tid) * SPLIT + s] =
            red[0][tid] + red[1][tid] + red[2][tid] + red[3][tid];
    }
    if (tid == V && n == 0) {
        p2partial[s] = redp[0] + redp[1] + redp[2] + redp[3];
    }
}

// Kernel 2: per-sample top-12 (stable desc on raw sums — monotone-equivalent under
// the positive normalization scale), y_hat = sigmoid(normalized). 64 x 64.
__global__ __launch_bounds__(64) void k_topk(const float* __restrict__ partial_t,
                                             const float* __restrict__ p2partial,
                                             int* __restrict__ idxbuf,
                                             float* __restrict__ yhatbuf) {
    const int n = blockIdx.x, lane = threadIdx.x;
    float s2 = 0.f;
    #pragma unroll
    for (int i = 0; i < SPLIT; ++i) s2 += p2partial[i];

    float my = 0.f;
    if (lane < V) {
        const float4* pb = (const float4*)(partial_t + ((size_t)n * V + lane) * SPLIT);
        #pragma unroll
        for (int i = 0; i < SPLIT / 4; ++i) {
            float4 q = pb[i];
            my += q.x + q.y + q.z + q.w;
        }
    }
    int rank = 0;
    #pragma unroll
    for (int u = 0; u < V; ++u) {
        const float yu = __shfl(my, u);
        if (yu > my || (yu == my && u < lane)) ++rank;
    }
    if (lane < V && rank < VK) {
        idxbuf[n * VK + rank]  = lane;
        yhatbuf[n * VK + rank] = 1.0f / (1.0f + expf(-my * rsqrtf(s2)));
    }
}

// Kernel 3: blocks [0,8192): gather+scale, barrier-free per-wave regions, NT stores
//           (xout never re-read -> don't evict x from L3).
//           blocks [8192,8384): A_out[n,k,a,b] = sum_m A[n,k,ia,m]*A[n,k,m,ib], wave 0.
__global__ __launch_bounds__(256) void k_gather_aout(const float* __restrict__ x,
                                                     const float* __restrict__ A,
                                                     const int* __restrict__ idxbuf,
                                                     const float* __restrict__ yhatbuf,
                                                     float* __restrict__ xout,
                                                     float* __restrict__ aout) {
    __shared__ float lds[ROWS * V];          // 25600 B (aout path uses first 625)
    __shared__ int   swidx[4][VK];
    __shared__ float swyh[4][VK];
    const int tid = threadIdx.x, wave = tid >> 6, lane = tid & 63;

    if (blockIdx.x < (unsigned)NBLK_G) {
        const int n  = blockIdx.x >> 7;          // 128 tiles per sample
        const int r0 = (blockIdx.x & 127) << 8;  // row base within sample

        // 1) issue this wave's 64-row stage DMA
        stage_wave(x + ((size_t)n * CT + r0) * V, lds, wave, lane);
        // 2) fetch idx/yhat (L2-hot) into wave-local LDS scratch while DMA flies
        if (lane < VK) {
            swidx[wave][lane] = idxbuf[n * VK + lane];
            swyh[wave][lane]  = yhatbuf[n * VK + lane];
        }
        // 3) same-wave completion: DMA + scratch ds_writes
        asm volatile("s_waitcnt vmcnt(0) lgkmcnt(0)" ::: "memory");

        // 4) wave w writes output f4s [192w,192w+192) covering its own 64 rows
        f32x4* dst = (f32x4*)(xout + ((size_t)n * CT + r0) * VK);
        #pragma unroll
        for (int j = 0; j < 3; ++j) {
            const int f   = 192 * wave + 64 * j + lane;
            const int row = f / 3;
            const int c0  = (f % 3) * 4;
            f32x4 o;
            o.x = lds[row * V + swidx[wave][c0 + 0]] * swyh[wave][c0 + 0];
            o.y = lds[row * V + swidx[wave][c0 + 1]] * swyh[wave][c0 + 1];
            o.z = lds[row * V + swidx[wave][c0 + 2]] * swyh[wave][c0 + 2];
            o.w = lds[row * V + swidx[wave][c0 + 3]] * swyh[wave][c0 + 3];
            __builtin_nontemporal_store(o, &dst[f]);   // coalesced, no-allocate
        }
    } else {
        if (wave != 0) return;                   // tiny blocks: single wave, no barrier
        const int b2 = blockIdx.x - NBLK_G;      // [0, 192)
        const int n  = b2 / K;
        const int k  = b2 % K;
        if (lane < VK) swidx[0][lane] = idxbuf[n * VK + lane];
        const float* Ak = A + ((size_t)n * K + k) * V * V;
        for (int i = lane; i < V * V; i += 64) lds[i] = Ak[i];
        asm volatile("s_waitcnt vmcnt(0) lgkmcnt(0)" ::: "memory");
        for (int o = lane; o < VK * VK; o += 64) {
            const int a  = o / VK, bc = o % VK;
            const int ia = swidx[0][a], ib = swidx[0][bc];
            float ssum = 0.f;
            #pragma unroll
            for (int m = 0; m < V; ++m) ssum += lds[ia * V + m] * lds[m * V + ib];
            __builtin_nontemporal_store(ssum, &aout[((size_t)n * K + k) * VK * VK + o]);
        }
    }
}

extern "C" void kernel_launch(void* const* d_in, const int* in_sizes, int n_in,
                              void* d_out, int out_size, void* d_ws, size_t ws_size,
                              hipStream_t stream) {
    const float* x = (const float*)d_in[0];
    const float* A = (const float*)d_in[1];
    const float* p = (const float*)d_in[2];

    float* xout = (float*)d_out;                       // N*CT*VK floats
    float* aout = xout + (size_t)N * CT * VK;          // N*K*VK*VK floats

    char* ws = (char*)d_ws;
    float* partial_t = (float*)(ws);                   // 51200 floats [n][v][s]
    float* p2partial = (float*)(ws + 204800);          // 32 floats
    float* yhatbuf   = (float*)(ws + 204928);          // 768 floats
    int*   idxbuf    = (int*)  (ws + 208000);          // 768 ints

    k_scores<<<N * SPLIT, 256, 0, stream>>>(x, p, partial_t, p2partial);
    k_topk<<<N, 64, 0, stream>>>(partial_t, p2partial, idxbuf, yhatbuf);
    k_gather_aout<<<NBLK_G + N * K, 256, 0, stream>>>(x, A, idxbuf, yhatbuf, xout, aout);
}